// Round 1
// baseline (10444.466 us; speedup 1.0000x reference)
//
#include <hip/hip_runtime.h>
#include <math.h>

// Workspace layout (floats)
#define WS_H1A   0
#define WS_H2A   65536
#define WS_C1    131072
#define WS_C2    196608
#define WS_H1B   262144
#define WS_H2B   327680
#define WS_VATT  393216
#define WS_X1    458752   // 2048*4096 = 8388608 floats

__device__ __forceinline__ float sigm(float x) { return 1.f / (1.f + expf(-x)); }

// Zero h1a, h2a, c1, c2 (first 262144 floats of ws)
__global__ __launch_bounds__(256) void zero_kernel(float* __restrict__ p) {
    int i = (blockIdx.x * 256 + threadIdx.x) * 4;
    *(float4*)(p + i) = make_float4(0.f, 0.f, 0.f, 0.f);
}

// X1[p][j] = emb[tok[p]] . w_ih1[j] + b_ih1[j] + b_hh1[j]
// p in [0,2048), j in [0,4096), K=1024. Tiled 64x64, BK=16, 256 thr, 4x4 micro.
__global__ __launch_bounds__(256) void x1_gemm(
    const int* __restrict__ tokens, const float* __restrict__ emb,
    const float* __restrict__ w_ih1, const float* __restrict__ b_ih1,
    const float* __restrict__ b_hh1, float* __restrict__ X1)
{
    __shared__ float as[16 * 68];
    __shared__ float bs[16 * 68];
    __shared__ int tok[64];
    int tid = threadIdx.x;
    int j0 = blockIdx.x * 64;
    int p0 = blockIdx.y * 64;
    if (tid < 64) tok[tid] = tokens[p0 + tid];
    __syncthreads();

    int row = tid >> 2;      // 0..63
    int kq  = tid & 3;       // 0..3
    const float* arow = emb   + (size_t)tok[row] * 1024 + kq * 4;
    const float* brow = w_ih1 + (size_t)(j0 + row) * 1024 + kq * 4;
    int tx = tid & 15, ty = tid >> 4;

    float acc[4][4] = {};
    for (int kb = 0; kb < 64; kb++) {
        float4 a4 = *(const float4*)(arow + kb * 16);
        float4 b4 = *(const float4*)(brow + kb * 16);
        __syncthreads();
        as[(kq * 4 + 0) * 68 + row] = a4.x;
        as[(kq * 4 + 1) * 68 + row] = a4.y;
        as[(kq * 4 + 2) * 68 + row] = a4.z;
        as[(kq * 4 + 3) * 68 + row] = a4.w;
        bs[(kq * 4 + 0) * 68 + row] = b4.x;
        bs[(kq * 4 + 1) * 68 + row] = b4.y;
        bs[(kq * 4 + 2) * 68 + row] = b4.z;
        bs[(kq * 4 + 3) * 68 + row] = b4.w;
        __syncthreads();
        #pragma unroll
        for (int kk = 0; kk < 16; kk++) {
            float4 av = *(const float4*)&as[kk * 68 + ty * 4];
            float4 bv = *(const float4*)&bs[kk * 68 + tx * 4];
            acc[0][0] += av.x * bv.x; acc[0][1] += av.x * bv.y;
            acc[0][2] += av.x * bv.z; acc[0][3] += av.x * bv.w;
            acc[1][0] += av.y * bv.x; acc[1][1] += av.y * bv.y;
            acc[1][2] += av.y * bv.z; acc[1][3] += av.y * bv.w;
            acc[2][0] += av.z * bv.x; acc[2][1] += av.z * bv.y;
            acc[2][2] += av.z * bv.z; acc[2][3] += av.z * bv.w;
            acc[3][0] += av.w * bv.x; acc[3][1] += av.w * bv.y;
            acc[3][2] += av.w * bv.z; acc[3][3] += av.w * bv.w;
        }
    }
    int j = j0 + tx * 4;
    float4 bi = *(const float4*)(b_ih1 + j);
    float4 bh = *(const float4*)(b_hh1 + j);
    #pragma unroll
    for (int r = 0; r < 4; r++) {
        int p = p0 + ty * 4 + r;
        float4 o;
        o.x = acc[r][0] + bi.x + bh.x;
        o.y = acc[r][1] + bi.y + bh.y;
        o.z = acc[r][2] + bi.z + bh.z;
        o.w = acc[r][3] + bi.w + bh.w;
        *(float4*)(X1 + (size_t)p * 4096 + j) = o;
    }
}

// cell1: thread (n=lane, d) computes 4 gate dot-products over h_prev, fused LSTM epilogue.
// grid 256, block 256 (64 n-lanes x 4 d per block).
__global__ __launch_bounds__(256) void cell1_step(
    const float* __restrict__ x1t,    // 64 x 4096 (includes both biases)
    const float* __restrict__ h_prev, // 64 x 1024
    const float* __restrict__ w_hh1,  // 4096 x 1024
    float* __restrict__ c1,           // 64 x 1024 (in-place)
    float* __restrict__ h_out)        // 64 x 1024
{
    int tid = threadIdx.x;
    int n = tid & 63;
    int wid = __builtin_amdgcn_readfirstlane(tid >> 6);
    int d = blockIdx.x * 4 + wid;

    const float* hrow = h_prev + n * 1024;
    const float* wi = w_hh1 + (size_t)d * 1024;
    const float* wf = wi + (size_t)1024 * 1024;
    const float* wg = wi + (size_t)2048 * 1024;
    const float* wo = wi + (size_t)3072 * 1024;

    float ai = 0.f, af = 0.f, ag = 0.f, ao = 0.f;
    #pragma unroll 4
    for (int k = 0; k < 1024; k += 4) {
        float4 h4 = *(const float4*)(hrow + k);
        float4 A = *(const float4*)(wi + k);
        float4 B = *(const float4*)(wf + k);
        float4 C = *(const float4*)(wg + k);
        float4 D = *(const float4*)(wo + k);
        ai += h4.x * A.x + h4.y * A.y + h4.z * A.z + h4.w * A.w;
        af += h4.x * B.x + h4.y * B.y + h4.z * B.z + h4.w * B.w;
        ag += h4.x * C.x + h4.y * C.y + h4.z * C.z + h4.w * C.w;
        ao += h4.x * D.x + h4.y * D.y + h4.z * D.z + h4.w * D.w;
    }
    const float* xr = x1t + n * 4096;
    float gi = ai + xr[d];
    float gf = af + xr[d + 1024];
    float gg = ag + xr[d + 2048];
    float go = ao + xr[d + 3072];
    float cold = c1[n * 1024 + d];
    float cn = sigm(gf) * cold + sigm(gi) * tanhf(gg);
    c1[n * 1024 + d] = cn;
    h_out[n * 1024 + d] = sigm(go) * tanhf(cn);
}

// attention: one block per sample n. Wave w handles l = w, w+4, ...
// Each F row read once: used for alpha (shuffle-reduce) and v_att accumulate.
__global__ __launch_bounds__(256) void attention_step(
    const float* __restrict__ h1,  // 64 x 1024 (current)
    const float* __restrict__ F,   // 64 x 196 x 1024
    float* __restrict__ v_att)     // 64 x 1024
{
    __shared__ float vs[4][1024];
    int n = blockIdx.x;
    int tid = threadIdx.x, lane = tid & 63, w = tid >> 6;

    const float* hrow = h1 + n * 1024 + lane * 16;
    float hreg[16];
    #pragma unroll
    for (int j = 0; j < 4; j++) {
        float4 t = *(const float4*)(hrow + j * 4);
        hreg[4 * j + 0] = t.x; hreg[4 * j + 1] = t.y;
        hreg[4 * j + 2] = t.z; hreg[4 * j + 3] = t.w;
    }
    float vacc[16];
    #pragma unroll
    for (int j = 0; j < 16; j++) vacc[j] = 0.f;

    const float* Fn = F + (size_t)n * 196 * 1024;
    for (int l = w; l < 196; l += 4) {
        const float* frow = Fn + (size_t)l * 1024 + lane * 16;
        float f[16];
        #pragma unroll
        for (int j = 0; j < 4; j++) {
            float4 t = *(const float4*)(frow + j * 4);
            f[4 * j + 0] = t.x; f[4 * j + 1] = t.y;
            f[4 * j + 2] = t.z; f[4 * j + 3] = t.w;
        }
        float p = 0.f;
        #pragma unroll
        for (int j = 0; j < 16; j++) p += f[j] * hreg[j];
        #pragma unroll
        for (int off = 32; off > 0; off >>= 1) p += __shfl_xor(p, off, 64);
        #pragma unroll
        for (int j = 0; j < 16; j++) vacc[j] += p * f[j];
    }
    #pragma unroll
    for (int j = 0; j < 4; j++) {
        float4 t;
        t.x = vacc[4 * j + 0]; t.y = vacc[4 * j + 1];
        t.z = vacc[4 * j + 2]; t.w = vacc[4 * j + 3];
        *(float4*)&vs[w][lane * 16 + j * 4] = t;
    }
    __syncthreads();
    int d0 = tid * 4;
    float4 a = *(const float4*)&vs[0][d0];
    float4 b = *(const float4*)&vs[1][d0];
    float4 c = *(const float4*)&vs[2][d0];
    float4 e = *(const float4*)&vs[3][d0];
    float4 o;
    o.x = a.x + b.x + c.x + e.x;
    o.y = a.y + b.y + c.y + e.y;
    o.z = a.z + b.z + c.z + e.z;
    o.w = a.w + b.w + c.w + e.w;
    *(float4*)(v_att + n * 1024 + d0) = o;
}

// cell2: x2 = [v_att | h1], plus h2_prev recurrent. K = 3072 total, fused epilogue.
__global__ __launch_bounds__(256) void cell2_step(
    const float* __restrict__ v_att,   // 64 x 1024
    const float* __restrict__ h1,      // 64 x 1024 (current)
    const float* __restrict__ h2_prev, // 64 x 1024
    const float* __restrict__ w_ih2,   // 4096 x 2048
    const float* __restrict__ w_hh2,   // 4096 x 1024
    const float* __restrict__ b_ih2, const float* __restrict__ b_hh2,
    float* __restrict__ c2,            // 64 x 1024 (in-place)
    float* __restrict__ h2_out,        // 64 x 1024
    float* __restrict__ out_t)         // out + t*65536
{
    int tid = threadIdx.x;
    int n = tid & 63;
    int wid = __builtin_amdgcn_readfirstlane(tid >> 6);
    int d = blockIdx.x * 4 + wid;

    const float* vrow  = v_att  + n * 1024;
    const float* h1row = h1     + n * 1024;
    const float* h2row = h2_prev + n * 1024;
    const float* wx0 = w_ih2 + (size_t)(d)        * 2048;
    const float* wx1 = w_ih2 + (size_t)(d + 1024) * 2048;
    const float* wx2 = w_ih2 + (size_t)(d + 2048) * 2048;
    const float* wx3 = w_ih2 + (size_t)(d + 3072) * 2048;
    const float* wh0 = w_hh2 + (size_t)(d)        * 1024;
    const float* wh1 = w_hh2 + (size_t)(d + 1024) * 1024;
    const float* wh2 = w_hh2 + (size_t)(d + 2048) * 1024;
    const float* wh3 = w_hh2 + (size_t)(d + 3072) * 1024;

    float ai = 0.f, af = 0.f, ag = 0.f, ao = 0.f;
    // segment 1: v_att vs w_ih2[:, 0:1024]
    #pragma unroll 2
    for (int k = 0; k < 1024; k += 4) {
        float4 x4 = *(const float4*)(vrow + k);
        float4 A = *(const float4*)(wx0 + k);
        float4 B = *(const float4*)(wx1 + k);
        float4 C = *(const float4*)(wx2 + k);
        float4 D = *(const float4*)(wx3 + k);
        ai += x4.x * A.x + x4.y * A.y + x4.z * A.z + x4.w * A.w;
        af += x4.x * B.x + x4.y * B.y + x4.z * B.z + x4.w * B.w;
        ag += x4.x * C.x + x4.y * C.y + x4.z * C.z + x4.w * C.w;
        ao += x4.x * D.x + x4.y * D.y + x4.z * D.z + x4.w * D.w;
    }
    // segment 2: h1 vs w_ih2[:, 1024:2048]
    #pragma unroll 2
    for (int k = 0; k < 1024; k += 4) {
        float4 x4 = *(const float4*)(h1row + k);
        float4 A = *(const float4*)(wx0 + 1024 + k);
        float4 B = *(const float4*)(wx1 + 1024 + k);
        float4 C = *(const float4*)(wx2 + 1024 + k);
        float4 D = *(const float4*)(wx3 + 1024 + k);
        ai += x4.x * A.x + x4.y * A.y + x4.z * A.z + x4.w * A.w;
        af += x4.x * B.x + x4.y * B.y + x4.z * B.z + x4.w * B.w;
        ag += x4.x * C.x + x4.y * C.y + x4.z * C.z + x4.w * C.w;
        ao += x4.x * D.x + x4.y * D.y + x4.z * D.z + x4.w * D.w;
    }
    // segment 3: h2_prev vs w_hh2
    #pragma unroll 2
    for (int k = 0; k < 1024; k += 4) {
        float4 x4 = *(const float4*)(h2row + k);
        float4 A = *(const float4*)(wh0 + k);
        float4 B = *(const float4*)(wh1 + k);
        float4 C = *(const float4*)(wh2 + k);
        float4 D = *(const float4*)(wh3 + k);
        ai += x4.x * A.x + x4.y * A.y + x4.z * A.z + x4.w * A.w;
        af += x4.x * B.x + x4.y * B.y + x4.z * B.z + x4.w * B.w;
        ag += x4.x * C.x + x4.y * C.y + x4.z * C.z + x4.w * C.w;
        ao += x4.x * D.x + x4.y * D.y + x4.z * D.z + x4.w * D.w;
    }
    float gi = ai + b_ih2[d]        + b_hh2[d];
    float gf = af + b_ih2[d + 1024] + b_hh2[d + 1024];
    float gg = ag + b_ih2[d + 2048] + b_hh2[d + 2048];
    float go = ao + b_ih2[d + 3072] + b_hh2[d + 3072];
    float cold = c2[n * 1024 + d];
    float cn = sigm(gf) * cold + sigm(gi) * tanhf(gg);
    c2[n * 1024 + d] = cn;
    float hn = sigm(go) * tanhf(cn);
    h2_out[n * 1024 + d] = hn;
    out_t[n * 1024 + d] = hn;
}

extern "C" void kernel_launch(void* const* d_in, const int* in_sizes, int n_in,
                              void* d_out, int out_size, void* d_ws, size_t ws_size,
                              hipStream_t stream)
{
    const int*   tokens = (const int*)d_in[0];
    const float* imgf   = (const float*)d_in[1];
    const float* emb    = (const float*)d_in[2];
    const float* w_ih1  = (const float*)d_in[3];
    const float* w_hh1  = (const float*)d_in[4];
    const float* b_ih1  = (const float*)d_in[5];
    const float* b_hh1  = (const float*)d_in[6];
    const float* w_ih2  = (const float*)d_in[7];
    const float* w_hh2  = (const float*)d_in[8];
    const float* b_ih2  = (const float*)d_in[9];
    const float* b_hh2  = (const float*)d_in[10];
    float* out = (float*)d_out;
    float* ws  = (float*)d_ws;

    float* h1a  = ws + WS_H1A;
    float* h2a  = ws + WS_H2A;
    float* c1   = ws + WS_C1;
    float* c2   = ws + WS_C2;
    float* h1b  = ws + WS_H1B;
    float* h2b  = ws + WS_H2B;
    float* vatt = ws + WS_VATT;
    float* X1   = ws + WS_X1;

    zero_kernel<<<256, 256, 0, stream>>>(ws);
    x1_gemm<<<dim3(64, 32), 256, 0, stream>>>(tokens, emb, w_ih1, b_ih1, b_hh1, X1);

    for (int t = 0; t < 32; t++) {
        float* h1p = (t & 1) ? h1b : h1a;
        float* h1c = (t & 1) ? h1a : h1b;
        float* h2p = (t & 1) ? h2b : h2a;
        float* h2c = (t & 1) ? h2a : h2b;
        cell1_step<<<256, 256, 0, stream>>>(X1 + (size_t)t * 262144, h1p, w_hh1, c1, h1c);
        attention_step<<<64, 256, 0, stream>>>(h1c, imgf, vatt);
        cell2_step<<<256, 256, 0, stream>>>(vatt, h1c, h2p, w_ih2, w_hh2,
                                            b_ih2, b_hh2, c2, h2c,
                                            out + (size_t)t * 65536);
    }
}

// Round 3
// 1189.420 us; speedup vs baseline: 8.7811x; 8.7811x over previous
//
#include <hip/hip_runtime.h>
#include <math.h>

// ---------------- types ----------------
typedef __attribute__((ext_vector_type(8))) short bf16x8;
typedef __attribute__((ext_vector_type(4))) short short4v;
typedef __attribute__((ext_vector_type(4))) float f32x4;

__device__ __forceinline__ float sigm(float x) { return 1.f / (1.f + expf(-x)); }

__device__ __forceinline__ float bf2f(short x) {
    unsigned u = ((unsigned)(unsigned short)x) << 16;
    float f; __builtin_memcpy(&f, &u, 4); return f;
}
__device__ __forceinline__ short f2bf(float f) {
    unsigned u; __builtin_memcpy(&u, &f, 4);
    unsigned r = (u + 0x7fffu + ((u >> 16) & 1u)) >> 16;
    return (short)r;
}

// ---------------- workspace layout (byte offsets) ----------------
#define OFF_C1      0u           // 64x1024 f32   262144
#define OFF_C2      262144u      // 64x1024 f32   262144
#define OFF_H2A     524288u      // 64x1024 bf16  131072
#define OFF_H2B     655360u      // 64x1024 bf16  131072
#define OFF_H1HI    786432u      // 33 x 64x1024 bf16  4325376
#define OFF_H1LO    5111808u     // 33 x 64x1024 bf16  4325376
#define OFF_H1F     9437184u     // 32 x 64x1024 f32   8388608
#define OFF_X0HI    17825792u    // 2048x1024 bf16 4194304  (aliased by VHI later)
#define OFF_X0LO    22020096u    // 2048x1024 bf16 4194304  (aliased by VLO later)
#define OFF_B1      26214400u    // 4096 f32 16384
#define OFF_B2      26230784u    // 4096 f32 16384
#define OFF_WHH1HI  26247168u    // 4096x1024 bf16 8388608
#define OFF_WHH1LO  34635776u
#define OFF_WIH1HI  43024384u
#define OFF_WIH1LO  51412992u
#define OFF_WHH2HI  59801600u
#define OFF_WVHI    68190208u
#define OFF_WVLO    76578816u
#define OFF_WH2HI   84967424u
#define OFF_X12     93356032u    // 2048x4096 f32 33554432 (also lo-dump during prep)
// total ~121 MB

// ---------------- prep kernels ----------------
__global__ __launch_bounds__(256) void zero_ws(float4* __restrict__ p) {
    int i = blockIdx.x * 256 + threadIdx.x;
    p[i] = make_float4(0.f, 0.f, 0.f, 0.f);
}

// 4096 x 1024 slice of src (row stride rs, col offset co), gate-interleaved rows
// (dst row j' = d*4+g from src row g*1024+d), split into hi/lo bf16.
__global__ __launch_bounds__(256) void perm_w_split(const float* __restrict__ src,
                                                    short* __restrict__ hi,
                                                    short* __restrict__ lo,
                                                    int rs, int co) {
    int idx = blockIdx.x * 256 + threadIdx.x;   // 4096 blocks
    int jp = idx >> 8;
    int kq = idx & 255;
    int jsrc = (jp & 3) * 1024 + (jp >> 2);
    float4 v = *(const float4*)(src + (size_t)jsrc * rs + co + kq * 4);
    float a[4] = {v.x, v.y, v.z, v.w};
    short4v h, l;
    #pragma unroll
    for (int e = 0; e < 4; e++) {
        short q = f2bf(a[e]);
        h[e] = q;
        l[e] = f2bf(a[e] - bf2f(q));
    }
    *(short4v*)(hi + (size_t)jp * 1024 + kq * 4) = h;
    *(short4v*)(lo + (size_t)jp * 1024 + kq * 4) = l;
}

__global__ __launch_bounds__(256) void bias_prep(
    const float* __restrict__ bi1, const float* __restrict__ bh1,
    const float* __restrict__ bi2, const float* __restrict__ bh2,
    float* __restrict__ b1p, float* __restrict__ b2p) {
    int jp = blockIdx.x * 256 + threadIdx.x;     // 16 blocks
    int j = (jp & 3) * 1024 + (jp >> 2);
    b1p[jp] = bi1[j] + bh1[j];
    b2p[jp] = bi2[j] + bh2[j];
}

__global__ __launch_bounds__(256) void gather_x0_split(
    const int* __restrict__ tokens, const float* __restrict__ emb,
    short* __restrict__ hi, short* __restrict__ lo) {
    int idx = blockIdx.x * 256 + threadIdx.x;    // 2048 blocks
    int p = idx >> 8;
    int k0 = (idx & 255) * 4;
    int tok = tokens[p];
    float4 v = *(const float4*)(emb + (size_t)tok * 1024 + k0);
    float a[4] = {v.x, v.y, v.z, v.w};
    short4v h, l;
    #pragma unroll
    for (int e = 0; e < 4; e++) {
        short q = f2bf(a[e]);
        h[e] = q;
        l[e] = f2bf(a[e] - bf2f(q));
    }
    *(short4v*)(hi + (size_t)p * 1024 + k0) = h;
    *(short4v*)(lo + (size_t)p * 1024 + k0) = l;
}

// ---------------- big GEMM: C[2048][4096] = sum_seg Aseg @ Bseg^T + bias -------
// Segments of K=1024 each (bf16, row stride 1024), selected by k0>>10.
// 128x128 tile, BK=32, 256 thr, MFMA 16x16x32.
__global__ __launch_bounds__(256) void big_gemm(
    const short* __restrict__ A0, const short* __restrict__ A1s,
    const short* __restrict__ A2s, const short* __restrict__ A3s,
    const short* __restrict__ B0, const short* __restrict__ B1s,
    const short* __restrict__ B2s, const short* __restrict__ B3s,
    const float* __restrict__ bias, float* __restrict__ C, int K) {
    __shared__ short As[128 * 40];
    __shared__ short Bs[128 * 40];
    int tid = threadIdx.x;
    int n0 = blockIdx.x * 128;
    int m0 = blockIdx.y * 128;
    int lane = tid & 63, w = tid >> 6;
    int wm = (w >> 1) * 64, wn = (w & 1) * 64;
    int quad = lane >> 4, l16 = lane & 15;
    int srow = tid >> 2;           // 0..63
    int skc = (tid & 3) * 8;       // k chunk within BK

    f32x4 acc[4][4];
    f32x4 z4 = {0.f, 0.f, 0.f, 0.f};
    #pragma unroll
    for (int i = 0; i < 4; i++)
        #pragma unroll
        for (int j = 0; j < 4; j++) acc[i][j] = z4;

    for (int k0 = 0; k0 < K; k0 += 32) {
        int seg = k0 >> 10;
        const short* Ab = (seg == 0) ? A0 : (seg == 1) ? A1s : (seg == 2) ? A2s : A3s;
        const short* Bb = (seg == 0) ? B0 : (seg == 1) ? B1s : (seg == 2) ? B2s : B3s;
        int kk = (k0 & 1023) + skc;
        const short* ga = Ab + (size_t)(m0 + srow) * 1024 + kk;
        const short* gb = Bb + (size_t)(n0 + srow) * 1024 + kk;
        bf16x8 av0 = *(const bf16x8*)ga;
        bf16x8 av1 = *(const bf16x8*)(ga + 64 * 1024);
        bf16x8 bv0 = *(const bf16x8*)gb;
        bf16x8 bv1 = *(const bf16x8*)(gb + 64 * 1024);
        __syncthreads();
        *(bf16x8*)&As[srow * 40 + skc] = av0;
        *(bf16x8*)&As[(srow + 64) * 40 + skc] = av1;
        *(bf16x8*)&Bs[srow * 40 + skc] = bv0;
        *(bf16x8*)&Bs[(srow + 64) * 40 + skc] = bv1;
        __syncthreads();
        bf16x8 af[4], bfr[4];
        #pragma unroll
        for (int im = 0; im < 4; im++)
            af[im] = *(const bf16x8*)&As[(wm + im * 16 + l16) * 40 + quad * 8];
        #pragma unroll
        for (int in = 0; in < 4; in++)
            bfr[in] = *(const bf16x8*)&Bs[(wn + in * 16 + l16) * 40 + quad * 8];
        #pragma unroll
        for (int im = 0; im < 4; im++)
            #pragma unroll
            for (int in = 0; in < 4; in++)
                acc[im][in] = __builtin_amdgcn_mfma_f32_16x16x32_bf16(
                    af[im], bfr[in], acc[im][in], 0, 0, 0);
    }
    #pragma unroll
    for (int in = 0; in < 4; in++) {
        int j = n0 + wn + in * 16 + l16;
        float bsv = bias[j];
        #pragma unroll
        for (int im = 0; im < 4; im++) {
            #pragma unroll
            for (int r = 0; r < 4; r++) {
                int p = m0 + wm + im * 16 + quad * 4 + r;
                C[(size_t)p * 4096 + j] = acc[im][in][r] + bsv;
            }
        }
    }
}

// ---------------- layer-1 cell step (compensated double-bf16) ----------------
// gates[64][4096] = Xg + (Ahi+Alo) @ (Whi+Wlo)^T  via 3-term split MFMA.
__global__ __launch_bounds__(256) void cell_step1(
    const short* __restrict__ Ahi, const short* __restrict__ Alo,
    const short* __restrict__ Whi, const short* __restrict__ Wlo,
    const float* __restrict__ Xg, float* __restrict__ c,
    short* __restrict__ hhi_o, short* __restrict__ hlo_o,
    float* __restrict__ hf_o) {
    __shared__ float red[4 * 64 * 16];
    int tid = threadIdx.x;
    int lane = tid & 63, w = tid >> 6;
    int quad = lane >> 4, l16 = lane & 15;
    int g = blockIdx.x;
    int kbase = w * 256;

    f32x4 acc[4];
    f32x4 z4 = {0.f, 0.f, 0.f, 0.f};
    acc[0] = z4; acc[1] = z4; acc[2] = z4; acc[3] = z4;

    const short* bh = Whi + (size_t)(g * 16 + l16) * 1024 + kbase + quad * 8;
    const short* bl = Wlo + (size_t)(g * 16 + l16) * 1024 + kbase + quad * 8;
    const short* ah = Ahi + (size_t)l16 * 1024 + kbase + quad * 8;
    const short* al = Alo + (size_t)l16 * 1024 + kbase + quad * 8;
    #pragma unroll
    for (int i = 0; i < 8; i++) {
        int k = i * 32;
        bf16x8 Bh = *(const bf16x8*)(bh + k);
        bf16x8 Bl = *(const bf16x8*)(bl + k);
        #pragma unroll
        for (int mt = 0; mt < 4; mt++) {
            bf16x8 Ah = *(const bf16x8*)(ah + mt * 16 * 1024 + k);
            bf16x8 Al = *(const bf16x8*)(al + mt * 16 * 1024 + k);
            acc[mt] = __builtin_amdgcn_mfma_f32_16x16x32_bf16(Ah, Bh, acc[mt], 0, 0, 0);
            acc[mt] = __builtin_amdgcn_mfma_f32_16x16x32_bf16(Al, Bh, acc[mt], 0, 0, 0);
            acc[mt] = __builtin_amdgcn_mfma_f32_16x16x32_bf16(Ah, Bl, acc[mt], 0, 0, 0);
        }
    }
    #pragma unroll
    for (int mt = 0; mt < 4; mt++)
        #pragma unroll
        for (int r = 0; r < 4; r++) {
            int s = mt * 16 + quad * 4 + r;
            red[(w * 64 + s) * 16 + l16] = acc[mt][r];
        }
    __syncthreads();

    int s = tid >> 2, dl = tid & 3;
    float gi = 0.f, gf = 0.f, gg = 0.f, go = 0.f;
    #pragma unroll
    for (int w2 = 0; w2 < 4; w2++) {
        const float* rp = &red[(w2 * 64 + s) * 16 + dl * 4];
        gi += rp[0]; gf += rp[1]; gg += rp[2]; go += rp[3];
    }
    float4 xg = *(const float4*)(Xg + (size_t)s * 4096 + g * 16 + dl * 4);
    gi += xg.x; gf += xg.y; gg += xg.z; go += xg.w;
    int d = g * 4 + dl;
    float cold = c[s * 1024 + d];
    float cn = sigm(gf) * cold + sigm(gi) * tanhf(gg);
    c[s * 1024 + d] = cn;
    float hn = sigm(go) * tanhf(cn);
    short q = f2bf(hn);
    hhi_o[s * 1024 + d] = q;
    hlo_o[s * 1024 + d] = f2bf(hn - bf2f(q));
    hf_o[s * 1024 + d] = hn;
}

// ---------------- layer-2 cell step (single bf16) ----------------
__global__ __launch_bounds__(256) void cell_step2(
    const short* __restrict__ Aprev, const short* __restrict__ W,
    const float* __restrict__ Xg, float* __restrict__ c,
    short* __restrict__ hout_bf, float* __restrict__ hout_f32) {
    __shared__ float red[4 * 64 * 16];
    int tid = threadIdx.x;
    int lane = tid & 63, w = tid >> 6;
    int quad = lane >> 4, l16 = lane & 15;
    int g = blockIdx.x;
    int kbase = w * 256;

    f32x4 acc[4];
    f32x4 z4 = {0.f, 0.f, 0.f, 0.f};
    acc[0] = z4; acc[1] = z4; acc[2] = z4; acc[3] = z4;

    const short* brow = W + (size_t)(g * 16 + l16) * 1024 + kbase + quad * 8;
    const short* arow = Aprev + (size_t)l16 * 1024 + kbase + quad * 8;
    #pragma unroll
    for (int i = 0; i < 8; i++) {
        int k = i * 32;
        bf16x8 b = *(const bf16x8*)(brow + k);
        #pragma unroll
        for (int mt = 0; mt < 4; mt++) {
            bf16x8 a = *(const bf16x8*)(arow + mt * 16 * 1024 + k);
            acc[mt] = __builtin_amdgcn_mfma_f32_16x16x32_bf16(a, b, acc[mt], 0, 0, 0);
        }
    }
    #pragma unroll
    for (int mt = 0; mt < 4; mt++)
        #pragma unroll
        for (int r = 0; r < 4; r++) {
            int s = mt * 16 + quad * 4 + r;
            red[(w * 64 + s) * 16 + l16] = acc[mt][r];
        }
    __syncthreads();

    int s = tid >> 2, dl = tid & 3;
    float gi = 0.f, gf = 0.f, gg = 0.f, go = 0.f;
    #pragma unroll
    for (int w2 = 0; w2 < 4; w2++) {
        const float* rp = &red[(w2 * 64 + s) * 16 + dl * 4];
        gi += rp[0]; gf += rp[1]; gg += rp[2]; go += rp[3];
    }
    float4 xg = *(const float4*)(Xg + (size_t)s * 4096 + g * 16 + dl * 4);
    gi += xg.x; gf += xg.y; gg += xg.z; go += xg.w;
    int d = g * 4 + dl;
    float cold = c[s * 1024 + d];
    float cn = sigm(gf) * cold + sigm(gi) * tanhf(gg);
    c[s * 1024 + d] = cn;
    float hn = sigm(go) * tanhf(cn);
    hout_bf[s * 1024 + d] = f2bf(hn);
    hout_f32[s * 1024 + d] = hn;
}

// ---------------- batched attention (fp32) ----------------
__global__ __launch_bounds__(256) void attn_batch(
    const float* __restrict__ H1f, const float* __restrict__ F,
    short* __restrict__ Vhi, short* __restrict__ Vlo) {
    __shared__ float vs[4][4][1024];
    int n = blockIdx.x, tg = blockIdx.y;
    int tid = threadIdx.x, lane = tid & 63, w = tid >> 6;

    float h[4][16];
    #pragma unroll
    for (int tt = 0; tt < 4; tt++) {
        const float* hp = H1f + ((size_t)((tg * 4 + tt) * 64 + n)) * 1024 + lane * 16;
        #pragma unroll
        for (int j = 0; j < 4; j++) {
            float4 v = *(const float4*)(hp + j * 4);
            h[tt][j * 4 + 0] = v.x; h[tt][j * 4 + 1] = v.y;
            h[tt][j * 4 + 2] = v.z; h[tt][j * 4 + 3] = v.w;
        }
    }
    float vacc[4][16];
    #pragma unroll
    for (int tt = 0; tt < 4; tt++)
        #pragma unroll
        for (int j = 0; j < 16; j++) vacc[tt][j] = 0.f;

    const float* Fn = F + ((size_t)n * 196) * 1024 + lane * 16;
    for (int l = w; l < 196; l += 4) {
        const float* fr = Fn + (size_t)l * 1024;
        float f[16];
        #pragma unroll
        for (int j = 0; j < 4; j++) {
            float4 v = *(const float4*)(fr + j * 4);
            f[j * 4 + 0] = v.x; f[j * 4 + 1] = v.y;
            f[j * 4 + 2] = v.z; f[j * 4 + 3] = v.w;
        }
        float p[4] = {0.f, 0.f, 0.f, 0.f};
        #pragma unroll
        for (int tt = 0; tt < 4; tt++)
            #pragma unroll
            for (int j = 0; j < 16; j++) p[tt] += f[j] * h[tt][j];
        #pragma unroll
        for (int off = 32; off > 0; off >>= 1) {
            #pragma unroll
            for (int tt = 0; tt < 4; tt++) p[tt] += __shfl_xor(p[tt], off, 64);
        }
        #pragma unroll
        for (int tt = 0; tt < 4; tt++)
            #pragma unroll
            for (int j = 0; j < 16; j++) vacc[tt][j] += p[tt] * f[j];
    }
    #pragma unroll
    for (int tt = 0; tt < 4; tt++)
        #pragma unroll
        for (int j4 = 0; j4 < 4; j4++) {
            float4 v;
            v.x = vacc[tt][j4 * 4 + 0]; v.y = vacc[tt][j4 * 4 + 1];
            v.z = vacc[tt][j4 * 4 + 2]; v.w = vacc[tt][j4 * 4 + 3];
            *(float4*)&vs[w][tt][lane * 16 + j4 * 4] = v;
        }
    __syncthreads();
    int d0 = tid * 4;
    #pragma unroll
    for (int tt = 0; tt < 4; tt++) {
        float4 a = *(const float4*)&vs[0][tt][d0];
        float4 b = *(const float4*)&vs[1][tt][d0];
        float4 cc = *(const float4*)&vs[2][tt][d0];
        float4 e = *(const float4*)&vs[3][tt][d0];
        float sv[4];
        sv[0] = a.x + b.x + cc.x + e.x;
        sv[1] = a.y + b.y + cc.y + e.y;
        sv[2] = a.z + b.z + cc.z + e.z;
        sv[3] = a.w + b.w + cc.w + e.w;
        short4v b1, b2;
        #pragma unroll
        for (int e2 = 0; e2 < 4; e2++) {
            short q = f2bf(sv[e2]);
            b1[e2] = q;
            b2[e2] = f2bf(sv[e2] - bf2f(q));
        }
        size_t row = ((size_t)(tg * 4 + tt) * 64 + n) * 1024 + d0;
        *(short4v*)(Vhi + row) = b1;
        *(short4v*)(Vlo + row) = b2;
    }
}

// ---------------- host launch ----------------
extern "C" void kernel_launch(void* const* d_in, const int* in_sizes, int n_in,
                              void* d_out, int out_size, void* d_ws, size_t ws_size,
                              hipStream_t stream) {
    const int*   tokens = (const int*)d_in[0];
    const float* imgf   = (const float*)d_in[1];
    const float* emb    = (const float*)d_in[2];
    const float* w_ih1  = (const float*)d_in[3];
    const float* w_hh1  = (const float*)d_in[4];
    const float* b_ih1  = (const float*)d_in[5];
    const float* b_hh1  = (const float*)d_in[6];
    const float* w_ih2  = (const float*)d_in[7];
    const float* w_hh2  = (const float*)d_in[8];
    const float* b_ih2  = (const float*)d_in[9];
    const float* b_hh2  = (const float*)d_in[10];
    float* out = (float*)d_out;
    char* ws = (char*)d_ws;

    float* c1     = (float*)(ws + OFF_C1);
    float* c2     = (float*)(ws + OFF_C2);
    short* h2a    = (short*)(ws + OFF_H2A);
    short* h2b    = (short*)(ws + OFF_H2B);
    short* H1hi   = (short*)(ws + OFF_H1HI);
    short* H1lo   = (short*)(ws + OFF_H1LO);
    float* H1f    = (float*)(ws + OFF_H1F);
    short* X0hi   = (short*)(ws + OFF_X0HI);
    short* X0lo   = (short*)(ws + OFF_X0LO);
    short* Vhi    = (short*)(ws + OFF_X0HI);   // alias (X0 dead after X1 GEMM)
    short* Vlo    = (short*)(ws + OFF_X0LO);
    float* bias1p = (float*)(ws + OFF_B1);
    float* bias2p = (float*)(ws + OFF_B2);
    short* whh1hi = (short*)(ws + OFF_WHH1HI);
    short* whh1lo = (short*)(ws + OFF_WHH1LO);
    short* wih1hi = (short*)(ws + OFF_WIH1HI);
    short* wih1lo = (short*)(ws + OFF_WIH1LO);
    short* whh2hi = (short*)(ws + OFF_WHH2HI);
    short* wvhi   = (short*)(ws + OFF_WVHI);
    short* wvlo   = (short*)(ws + OFF_WVLO);
    short* wh2hi  = (short*)(ws + OFF_WH2HI);
    float* X12    = (float*)(ws + OFF_X12);
    short* dump   = (short*)(ws + OFF_X12);    // prep-time scratch, overwritten later

    // prep
    zero_ws<<<192, 256, 0, stream>>>((float4*)(ws + OFF_C1));    // c1,c2,h2a,h2b
    zero_ws<<<32, 256, 0, stream>>>((float4*)(ws + OFF_H1HI));   // H1hi slot 0
    zero_ws<<<32, 256, 0, stream>>>((float4*)(ws + OFF_H1LO));   // H1lo slot 0
    perm_w_split<<<4096, 256, 0, stream>>>(w_hh1, whh1hi, whh1lo, 1024, 0);
    perm_w_split<<<4096, 256, 0, stream>>>(w_ih1, wih1hi, wih1lo, 1024, 0);
    perm_w_split<<<4096, 256, 0, stream>>>(w_hh2, whh2hi, dump, 1024, 0);
    perm_w_split<<<4096, 256, 0, stream>>>(w_ih2, wvhi, wvlo, 2048, 0);
    perm_w_split<<<4096, 256, 0, stream>>>(w_ih2, wh2hi, dump, 2048, 1024);
    bias_prep<<<16, 256, 0, stream>>>(b_ih1, b_hh1, b_ih2, b_hh2, bias1p, bias2p);
    gather_x0_split<<<2048, 256, 0, stream>>>(tokens, emb, X0hi, X0lo);

    // X1 = (X0hi+X0lo) @ (wih1hi+wih1lo)^T + bias1, triple-split, K=3072
    big_gemm<<<dim3(32, 16), 256, 0, stream>>>(
        X0hi, X0lo, X0hi, X0hi,
        wih1hi, wih1hi, wih1lo, wih1hi,
        bias1p, X12, 3072);

    // layer-1 recurrence (compensated)
    for (int t = 0; t < 32; t++) {
        cell_step1<<<256, 256, 0, stream>>>(
            H1hi + (size_t)t * 65536, H1lo + (size_t)t * 65536,
            whh1hi, whh1lo, X12 + (size_t)t * 262144, c1,
            H1hi + (size_t)(t + 1) * 65536, H1lo + (size_t)(t + 1) * 65536,
            H1f + (size_t)t * 65536);
    }

    // batched attention (fp32 in, compensated double-bf16 out)
    attn_batch<<<dim3(64, 8), 256, 0, stream>>>(H1f, imgf, Vhi, Vlo);

    // X2 = v@wv (triple-split) + h1@wh + bias2, K=4096
    big_gemm<<<dim3(32, 16), 256, 0, stream>>>(
        Vhi, Vlo, Vhi, H1hi + 65536,
        wvhi, wvhi, wvlo, wh2hi,
        bias2p, X12, 4096);

    // layer-2 recurrence (single bf16)
    for (int t = 0; t < 32; t++) {
        short* h2p = (t & 1) ? h2b : h2a;
        short* h2c = (t & 1) ? h2a : h2b;
        cell_step2<<<256, 256, 0, stream>>>(
            h2p, whh2hi, X12 + (size_t)t * 262144, c2,
            h2c, out + (size_t)t * 65536);
    }
}